// Round 4
// baseline (209.082 us; speedup 1.0000x reference)
//
#include <hip/hip_runtime.h>
#include <math.h>

// TimeEmbedding: out[b][i] = sin(t[b]*f_i) if i even else cos(t[b]*f_i),
// f_i = 10000^(-i/256), B=524288, D=512, f32 out (1 GiB). Write-BW-bound.
//
// R4 = R1 structure (dense write front) + PLAIN write-back stores (no nt).
//  - row = w + k*8192: all 8192 waves sweep one contiguous ~16MB band in
//    lockstep -> L2 evicts a dense rolling band -> DRAM row locality like
//    the 6.6 TB/s fill kernel.
//  - per row: two contiguous 1KB wave-stores (dwordx4).
//  - t[row] wave-uniform broadcast, prefetched 1 iteration ahead.
//  - 8 frequencies per lane loop-invariant (8 exp2 total per thread).

#define D_MODEL 512

typedef float f32x4 __attribute__((ext_vector_type(4)));

__device__ __forceinline__ float sin_rev(float r) {
    return __builtin_amdgcn_sinf(__builtin_amdgcn_fractf(r));  // HW sin takes revolutions
}
__device__ __forceinline__ float cos_rev(float r) {
    return __builtin_amdgcn_cosf(__builtin_amdgcn_fractf(r));
}

__global__ __launch_bounds__(256) void time_embed_kernel(
    const float* __restrict__ t, f32x4* __restrict__ out, int n_rows) {
    const int g = blockIdx.x * 256 + threadIdx.x;
    const int c = g & 63;                    // float4 slot within row
    const int w = g >> 6;                    // wave id = starting row
    const int nw = (gridDim.x * 256) >> 6;   // total waves = 8192

    const float LOG2_10000_OVER_256 = 0.051904345232615426f; // log2(10000)/256
    const float INV_2PI = 0.15915494309189535f;

    float fa[4], fb[4];
#pragma unroll
    for (int j = 0; j < 4; ++j) {
        fa[j] = __builtin_amdgcn_exp2f(-(float)(4 * c + j) * LOG2_10000_OVER_256) * INV_2PI;
        fb[j] = __builtin_amdgcn_exp2f(-(float)(4 * c + 256 + j) * LOG2_10000_OVER_256) * INV_2PI;
    }

    if (w >= n_rows) return;
    float tv = t[w];                         // wave-uniform broadcast load
    for (int r = w; r < n_rows; r += nw) {
        const int rn = r + nw;               // prefetch next row's t
        const float tn = t[rn < n_rows ? rn : r];

        f32x4 oa, ob;
        oa.x = sin_rev(tv * fa[0]);          // even col -> sin
        oa.y = cos_rev(tv * fa[1]);          // odd col  -> cos
        oa.z = sin_rev(tv * fa[2]);
        oa.w = cos_rev(tv * fa[3]);
        ob.x = sin_rev(tv * fb[0]);
        ob.y = cos_rev(tv * fb[1]);
        ob.z = sin_rev(tv * fb[2]);
        ob.w = cos_rev(tv * fb[3]);

        f32x4* rowp = out + (size_t)r * (D_MODEL / 4);
        rowp[c] = oa;                        // contiguous 1KB wave-store
        rowp[64 + c] = ob;                   // contiguous 1KB wave-store

        tv = tn;
    }
}

extern "C" void kernel_launch(void* const* d_in, const int* in_sizes, int n_in,
                              void* d_out, int out_size, void* d_ws, size_t ws_size,
                              hipStream_t stream) {
    const float* t = (const float*)d_in[0];
    f32x4* out = (f32x4*)d_out;
    const int n_rows = in_sizes[0];  // 524288
    // 2048 blocks x 256 threads = 8192 waves; 64 interleaved rows per wave
    time_embed_kernel<<<dim3(2048), dim3(256), 0, stream>>>(t, out, n_rows);
}

// Round 5
// 204.314 us; speedup vs baseline: 1.0233x; 1.0233x over previous
//
#include <hip/hip_runtime.h>
#include <math.h>

// TimeEmbedding: out[b][i] = sin(t[b]*f_i) if i even else cos(t[b]*f_i),
// f_i = 10000^(-i/256), B=524288, D=512, f32 out (1 GiB). Write-BW-bound.
//
// R5 = R3 chunked structure, scaled for fewer/longer write streams:
//  - 1024 blocks x 256 thr = 4096 waves; wave owns 128 CONSECUTIVE rows
//    (256 KB private stream)
//  - 8 rows per unrolled iteration -> 16 KB contiguous, 16 dwordx4
//    wave-stores in flight before loop-back; plain write-back stores
//  - t for 8 rows = two wave-uniform float4 broadcast loads, prefetched
//    one iteration ahead (branchless clamp)
//  - 8 frequencies per lane loop-invariant (8 exp2 total per thread)

#define D_MODEL 512

typedef float f32x4 __attribute__((ext_vector_type(4)));

__device__ __forceinline__ float sin_rev(float r) {
    return __builtin_amdgcn_sinf(__builtin_amdgcn_fractf(r));  // HW sin takes revolutions
}
__device__ __forceinline__ float cos_rev(float r) {
    return __builtin_amdgcn_cosf(__builtin_amdgcn_fractf(r));
}

__global__ __launch_bounds__(256) void time_embed_kernel(
    const float* __restrict__ t, f32x4* __restrict__ out, int n_rows) {
    const int g = blockIdx.x * 256 + threadIdx.x;
    const int c = g & 63;        // float4 slot within row (and +64 for 2nd half)
    const int w = g >> 6;        // wave id; wave owns rows [w*128, w*128+128)

    const float LOG2_10000_OVER_256 = 0.051904345232615426f; // log2(10000)/256
    const float INV_2PI = 0.15915494309189535f;

    float fa[4], fb[4];
#pragma unroll
    for (int j = 0; j < 4; ++j) {
        fa[j] = __builtin_amdgcn_exp2f(-(float)(4 * c + j) * LOG2_10000_OVER_256) * INV_2PI;
        fb[j] = __builtin_amdgcn_exp2f(-(float)(4 * c + 256 + j) * LOG2_10000_OVER_256) * INV_2PI;
    }

    const int row0 = w * 128;
    if (row0 >= n_rows) return;
    const float* tw = t + row0;                 // 128 t-values for this wave
    f32x4* outw = out + (size_t)row0 * (D_MODEL / 4);

    f32x4 ta = *(const f32x4*)(tw);             // wave-uniform broadcasts (iter 0)
    f32x4 tb = *(const f32x4*)(tw + 4);
    for (int q = 0; q < 16; ++q) {
        // branchless clamped prefetch of next iteration's 8 t-values
        const int qn = (q < 15) ? (q + 1) : q;
        const f32x4 tna = *(const f32x4*)(tw + 8 * qn);
        const f32x4 tnb = *(const f32x4*)(tw + 8 * qn + 4);

        f32x4* qp = outw + (size_t)(8 * q) * (D_MODEL / 4);
#pragma unroll
        for (int j = 0; j < 8; ++j) {           // j compile-time (rule #20)
            const float tv = (j < 4) ? ta[j & 3] : tb[j & 3];
            f32x4 oa, ob;
            oa.x = sin_rev(tv * fa[0]);         // even col -> sin
            oa.y = cos_rev(tv * fa[1]);         // odd col  -> cos
            oa.z = sin_rev(tv * fa[2]);
            oa.w = cos_rev(tv * fa[3]);
            ob.x = sin_rev(tv * fb[0]);
            ob.y = cos_rev(tv * fb[1]);
            ob.z = sin_rev(tv * fb[2]);
            ob.w = cos_rev(tv * fb[3]);
            f32x4* rowp = qp + (size_t)j * (D_MODEL / 4);
            rowp[c] = oa;                       // contiguous 1KB wave-store
            rowp[64 + c] = ob;                  // contiguous 1KB wave-store
        }
        ta = tna;
        tb = tnb;
    }
}

extern "C" void kernel_launch(void* const* d_in, const int* in_sizes, int n_in,
                              void* d_out, int out_size, void* d_ws, size_t ws_size,
                              hipStream_t stream) {
    const float* t = (const float*)d_in[0];
    f32x4* out = (f32x4*)d_out;
    const int n_rows = in_sizes[0];  // 524288 = 4096 waves * 128 rows
    time_embed_kernel<<<dim3(1024), dim3(256), 0, stream>>>(t, out, n_rows);
}

// Round 6
// 200.170 us; speedup vs baseline: 1.0445x; 1.0207x over previous
//
#include <hip/hip_runtime.h>
#include <math.h>

// TimeEmbedding: out[b][i] = sin(t[b]*f_i) if i even else cos(t[b]*f_i),
// f_i = 10000^(-i/256), B=524288, D=512, f32 out (1 GiB). Write-BW-bound.
//
// R6 = fill-mimic probe: low occupancy + zero-load steady-state loop.
//  - 256 blocks x 256 thr = 1024 waves (1/SIMD, 4/CU -- like the 6.5 TB/s
//    fill kernel's ~10.7% occupancy) -> ~1K concurrent DRAM write streams
//    instead of 4-8K (row-buffer locality at the HBM controllers).
//  - wave owns 512 consecutive rows (1 MB stream), processed in 8 segments
//    of 64 rows. Per segment: ONE per-lane coalesced t-load (prefetched a
//    segment ahead); rows broadcast via v_readlane (no memory op) -> the
//    inner loop is stores+VALU only, no vmcnt drain from loads.
//  - plain write-back dwordx4 stores, 2x contiguous 1KB per row.
//  - 8 frequencies per lane loop-invariant (8 exp2 total per thread).

#define D_MODEL 512

typedef float f32x4 __attribute__((ext_vector_type(4)));

__device__ __forceinline__ float sin_rev(float r) {
    return __builtin_amdgcn_sinf(__builtin_amdgcn_fractf(r));  // HW sin takes revolutions
}
__device__ __forceinline__ float cos_rev(float r) {
    return __builtin_amdgcn_cosf(__builtin_amdgcn_fractf(r));
}

__global__ __launch_bounds__(256) void time_embed_kernel(
    const float* __restrict__ t, f32x4* __restrict__ out, int n_rows) {
    const int g = blockIdx.x * 256 + threadIdx.x;
    const int lane = threadIdx.x & 63;       // float4 slot within row
    const int w = g >> 6;                    // wave id
    const int nw = (gridDim.x * 256) >> 6;   // 1024 waves

    const float LOG2_10000_OVER_256 = 0.051904345232615426f; // log2(10000)/256
    const float INV_2PI = 0.15915494309189535f;

    float fa[4], fb[4];
#pragma unroll
    for (int j = 0; j < 4; ++j) {
        fa[j] = __builtin_amdgcn_exp2f(-(float)(4 * lane + j) * LOG2_10000_OVER_256) * INV_2PI;
        fb[j] = __builtin_amdgcn_exp2f(-(float)(4 * lane + 256 + j) * LOG2_10000_OVER_256) * INV_2PI;
    }

    const int rows_per_wave = n_rows / nw;   // 512
    const int row0 = w * rows_per_wave;
    if (row0 >= n_rows) return;
    const float* tw = t + row0;
    f32x4* outw = out + (size_t)row0 * (D_MODEL / 4);

    const int nseg = rows_per_wave >> 6;     // 8 segments of 64 rows
    float tl = tw[lane];                     // segment 0: one t per lane
    for (int seg = 0; seg < nseg; ++seg) {
        const int segn = (seg + 1 < nseg) ? (seg + 1) : seg;
        const float tln = tw[segn * 64 + lane];  // prefetch next segment's t

        f32x4* sp = outw + (size_t)seg * 64 * (D_MODEL / 4);
        for (int r8 = 0; r8 < 8; ++r8) {         // 8 rows per unrolled body
#pragma unroll
            for (int j = 0; j < 8; ++j) {
                // wave-uniform broadcast of this row's t (no memory op)
                const float tv = __int_as_float(
                    __builtin_amdgcn_readlane(__float_as_int(tl), r8 * 8 + j));
                f32x4 oa, ob;
                oa.x = sin_rev(tv * fa[0]);  // even col -> sin
                oa.y = cos_rev(tv * fa[1]);  // odd col  -> cos
                oa.z = sin_rev(tv * fa[2]);
                oa.w = cos_rev(tv * fa[3]);
                ob.x = sin_rev(tv * fb[0]);
                ob.y = cos_rev(tv * fb[1]);
                ob.z = sin_rev(tv * fb[2]);
                ob.w = cos_rev(tv * fb[3]);
                f32x4* rowp = sp + (size_t)(r8 * 8 + j) * (D_MODEL / 4);
                rowp[lane] = oa;             // contiguous 1KB wave-store
                rowp[64 + lane] = ob;        // contiguous 1KB wave-store
            }
        }
        tl = tln;
    }
}

extern "C" void kernel_launch(void* const* d_in, const int* in_sizes, int n_in,
                              void* d_out, int out_size, void* d_ws, size_t ws_size,
                              hipStream_t stream) {
    const float* t = (const float*)d_in[0];
    f32x4* out = (f32x4*)d_out;
    const int n_rows = in_sizes[0];  // 524288 = 1024 waves * 512 rows
    time_embed_kernel<<<dim3(256), dim3(256), 0, stream>>>(t, out, n_rows);
}